// Round 18
// baseline (8401.676 us; speedup 1.0000x reference)
//
#include <hip/hip_runtime.h>
#include <math.h>

// Problem constants (match reference setup_inputs)
#define NTOT (1 << 19)   // 524288
#define NN1 512          // n1: fast time index,  k1: slow freq index
#define NN2 1024         // n2: slow time index,  k2: fast freq index
#define PM 4
#define NZ_STEPS 10

static const float DZv = 1.0e-3f;
static const float DTv = 0.01f;
static const float GAMMAv = 1.0e-3f;
static const float FRv = 0.18f;
static const float OMEGA0v = 1830.0f;

typedef float2 cplx;
__device__ inline cplx cmul(cplx a, cplx b) { return make_float2(a.x * b.x - a.y * b.y, a.x * b.y + a.y * b.x); }
__device__ inline cplx cadd(cplx a, cplx b) { return make_float2(a.x + b.x, a.y + b.y); }
__device__ inline cplx csub(cplx a, cplx b) { return make_float2(a.x - b.x, a.y - b.y); }
__device__ inline cplx cscale(cplx a, float s) { return make_float2(a.x * s, a.y * s); }
__device__ inline cplx conjc(cplx a) { return make_float2(a.x, -a.y); }
// e^{i * sgn * pi * a}
__device__ inline cplx expi_pi(float a, float sgn) {
    float s, c;
    sincospif(a, &s, &c);
    return make_float2(c, sgn * s);
}
// base-4 digit reversals (involutions)
__device__ inline int dig4rev10(int j) {
    return ((j & 3) << 8) | (((j >> 2) & 3) << 6) | (((j >> 4) & 3) << 4) | (((j >> 6) & 3) << 2) | ((j >> 8) & 3);
}
__device__ inline int b4rev8(int t) {
    return ((t & 3) << 6) | (((t >> 2) & 3) << 4) | (((t >> 4) & 3) << 2) | ((t >> 6) & 3);
}
__device__ inline int islot_512(int k1) { return ((k1 & 1) << 8) | b4rev8(k1 >> 1); }  // k1 -> slot

#define SK(q) ((q) + ((q) >> 4))   // LDS skew (float2 units)

// Wave-local fence: intra-wave LDS RAW needs only compile-time ordering.
__device__ inline void wfence() {
    asm volatile("" ::: "memory");
    __builtin_amdgcn_wave_barrier();
    asm volatile("" ::: "memory");
}

// ---- twiddle tables: T4[4] T16[16] T64[64] T256[256] R2[256] ----
#define TW_SZ 596
#define TWOFF(L) ((L) == 4 ? 0 : (L) == 16 ? 4 : (L) == 64 ? 20 : 84)
#define TWR2 340
__device__ inline void init_tw(cplx* tw, int tid) {
    for (int idx = tid; idx < TW_SZ; idx += 256) {
        float a;
        if (idx < 4) a = (float)idx * (0.5f / 4.0f);
        else if (idx < 20) a = (float)(idx - 4) * (0.5f / 16.0f);
        else if (idx < 84) a = (float)(idx - 20) * (0.5f / 64.0f);
        else if (idx < 340) a = (float)(idx - 84) * (0.5f / 256.0f);
        else a = (float)(idx - 340) * (1.0f / 256.0f);
        float s, c;
        sincospif(a, &s, &c);
        tw[idx] = make_float2(c, s);
    }
}
__device__ inline cplx twget(const cplx* tw, int off, int b, float SGN) {
    cplx t = tw[off + b];
    return make_float2(t.x, SGN * t.y);
}

// radix-4 butterflies with supplied twiddle w1 (w2=w1^2, w3=w1^3 derived)
__device__ inline void r4dif_w(cplx& x0, cplx& x1, cplx& x2, cplx& x3, cplx w1, float SGN) {
    cplx t0 = cadd(x0, x2), t1 = cadd(x1, x3), t2 = csub(x0, x2), t3 = csub(x1, x3);
    cplx ct3 = make_float2(-SGN * t3.y, SGN * t3.x);
    cplx w2 = cmul(w1, w1), w3 = cmul(w2, w1);
    x0 = cadd(t0, t1);
    x1 = cmul(cadd(t2, ct3), w1);
    x2 = cmul(csub(t0, t1), w2);
    x3 = cmul(csub(t2, ct3), w3);
}
__device__ inline void r4dif0(cplx& x0, cplx& x1, cplx& x2, cplx& x3, float SGN) {
    cplx t0 = cadd(x0, x2), t1 = cadd(x1, x3), t2 = csub(x0, x2), t3 = csub(x1, x3);
    cplx ct3 = make_float2(-SGN * t3.y, SGN * t3.x);
    x0 = cadd(t0, t1); x1 = cadd(t2, ct3); x2 = csub(t0, t1); x3 = csub(t2, ct3);
}
__device__ inline void r4dit_w(cplx& x0, cplx& x1, cplx& x2, cplx& x3, cplx w1, float SGN) {
    cplx w2 = cmul(w1, w1), w3 = cmul(w2, w1);
    cplx z1 = cmul(x1, w1), z2 = cmul(x2, w2), z3 = cmul(x3, w3);
    cplx t0 = cadd(x0, z2), t1 = cadd(z1, z3), t2 = csub(x0, z2), t3 = csub(z1, z3);
    cplx ct3 = make_float2(-SGN * t3.y, SGN * t3.x);
    x0 = cadd(t0, t1); x1 = cadd(t2, ct3); x2 = csub(t0, t1); x3 = csub(t2, ct3);
}
__device__ inline void r4dit0(cplx& x0, cplx& x1, cplx& x2, cplx& x3, float SGN) {
    cplx t0 = cadd(x0, x2), t1 = cadd(x1, x3), t2 = csub(x0, x2), t3 = csub(x1, x3);
    cplx ct3 = make_float2(-SGN * t3.y, SGN * t3.x);
    x0 = cadd(t0, t1); x1 = cadd(t2, ct3); x2 = csub(t0, t1); x3 = csub(t2, ct3);
}

// ---------------------------------------------------------------------------
// FFT line helpers (256-thread block, one 1024-pt line).
// ---------------------------------------------------------------------------
template <int ISGN>
__device__ inline void fft_j2n2(const cplx* gsrc, cplx* y, cplx* ld, const cplx* tw, int tid) {
    const float SGN = (float)ISGN;
    const float4* s4 = (const float4*)gsrc;
    float4 va = s4[2 * tid], vb = s4[2 * tid + 1];
    cplx y0 = make_float2(va.x, va.y), y1 = make_float2(va.z, va.w);
    cplx y2 = make_float2(vb.x, vb.y), y3 = make_float2(vb.z, vb.w);
    r4dit0(y0, y1, y2, y3, SGN);
    int q0 = 4 * tid;
    ld[SK(q0)] = y0; ld[SK(q0 + 1)] = y1; ld[SK(q0 + 2)] = y2; ld[SK(q0 + 3)] = y3;
    wfence();
    #pragma unroll
    for (int L = 4; L <= 64; L <<= 2) {
        int b = tid & (L - 1), g = tid / L;
        int p0 = g * 4 * L + b;
        cplx z0 = ld[SK(p0)], z1 = ld[SK(p0 + L)], z2 = ld[SK(p0 + 2 * L)], z3 = ld[SK(p0 + 3 * L)];
        r4dit_w(z0, z1, z2, z3, twget(tw, TWOFF(L), b, SGN), SGN);
        ld[SK(p0)] = z0; ld[SK(p0 + L)] = z1; ld[SK(p0 + 2 * L)] = z2; ld[SK(p0 + 3 * L)] = z3;
        if (L == 64) __syncthreads();  // next stage (L=256) reads cross-wave
        else wfence();
    }
    {
        int b = tid;
        cplx z0 = ld[SK(b)], z1 = ld[SK(b + 256)], z2 = ld[SK(b + 512)], z3 = ld[SK(b + 768)];
        r4dit_w(z0, z1, z2, z3, twget(tw, 84, b, SGN), SGN);
        y[0] = z0; y[1] = z1; y[2] = z2; y[3] = z3;
    }
}

// w0 = expi_pi(n1*dig4rev10(4*tid)*2/NTOT, SGN), dlt = expi_pi(n1/1024, SGN)
template <bool INV>
__device__ inline void fft_n22j(cplx* y, cplx* ld, const cplx* tw, int tid, cplx w0, cplx dlt, cplx* gdst) {
    const float SGN = INV ? 1.0f : -1.0f;
    r4dif_w(y[0], y[1], y[2], y[3], twget(tw, 84, tid, SGN), SGN);
    ld[SK(tid)] = y[0]; ld[SK(tid + 256)] = y[1]; ld[SK(tid + 512)] = y[2]; ld[SK(tid + 768)] = y[3];
    __syncthreads();  // scattered write, cross-wave readers below
    #pragma unroll
    for (int L = 64; L >= 4; L >>= 2) {
        int b = tid & (L - 1), g = tid / L;
        int p0 = g * 4 * L + b;
        cplx z0 = ld[SK(p0)], z1 = ld[SK(p0 + L)], z2 = ld[SK(p0 + 2 * L)], z3 = ld[SK(p0 + 3 * L)];
        r4dif_w(z0, z1, z2, z3, twget(tw, TWOFF(L), b, SGN), SGN);
        ld[SK(p0)] = z0; ld[SK(p0 + L)] = z1; ld[SK(p0 + 2 * L)] = z2; ld[SK(p0 + 3 * L)] = z3;
        wfence();  // L=64,16,4 and final read are wave-segment-local
    }
    {
        int p0 = 4 * tid;
        cplx z0 = ld[SK(p0)], z1 = ld[SK(p0 + 1)], z2 = ld[SK(p0 + 2)], z3 = ld[SK(p0 + 3)];
        r4dif0(z0, z1, z2, z3, SGN);
        cplx w = INV ? cscale(w0, 1.0f / (float)NTOT) : w0;
        cplx o0 = cmul(z0, w); w = cmul(w, dlt);
        cplx o1 = cmul(z1, w); w = cmul(w, dlt);
        cplx o2 = cmul(z2, w); w = cmul(w, dlt);
        cplx o3 = cmul(z3, w);
        float4* d4 = (float4*)(gdst + p0);
        d4[0] = make_float4(o0.x, o0.y, o1.x, o1.y);
        d4[1] = make_float4(o2.x, o2.y, o3.x, o3.y);
    }
}

// ---------------------------------------------------------------------------
// kA1: time layout xT[n1*1024+n2] -> Z[n1*1024+j] (prologue only)
// ---------------------------------------------------------------------------
template <bool INV>
__global__ __launch_bounds__(256) void kA1(const cplx* __restrict__ in, cplx* __restrict__ out) {
    __shared__ cplx ld[1024 + 64];
    __shared__ cplx tw[TW_SZ];
    int row = blockIdx.y;
    int n1 = blockIdx.x;
    int tid = threadIdx.x;
    const cplx* src = in + (size_t)row * NTOT;
    cplx* dst = out + (size_t)row * NTOT;
    size_t base = (size_t)n1 * NN2;
    cplx y[4];
    y[0] = src[base + tid];
    y[1] = src[base + tid + 256];
    y[2] = src[base + tid + 512];
    y[3] = src[base + tid + 768];
    init_tw(tw, tid);
    __syncthreads();
    const float SGN = INV ? 1.0f : -1.0f;
    cplx w0 = expi_pi((float)(n1 * dig4rev10(4 * tid)) * (2.0f / (float)NTOT), SGN);
    cplx dlt = expi_pi((float)n1 * (1.0f / 1024.0f), SGN);
    fft_n22j<INV>(y, ld, tw, tid, w0, dlt, dst + base);
}

// ---------------------------------------------------------------------------
// kM: middle kernel (512-pt FFT over n1, table multiply, FFT back, cross
//     twiddle, transposed store). Used for lin/lin^2/pref AND both conv
//     passes (U rows via gtab, W rows in-place via hrwc).
// ---------------------------------------------------------------------------
#define APPLY_CT(o, n1v)                                                        \
    {                                                                           \
        cplx W0 = expi_pi((float)((n1v) * k2b) * (2.0f / (float)NTOT), SGN_B);  \
        if (CONV) W0 = cscale(W0, 1.0f / (float)NTOT);                          \
        cplx P1 = expi_pi((float)(n1v) * (1.0f / 1024.0f), SGN_B);              \
        cplx P2 = expi_pi((float)(n1v) * (1.0f / 4096.0f), SGN_B);              \
        cplx wct = W0;                                                          \
        o[0] = cmul(o[0], wct);                                                 \
        wct = cmul(wct, P1); o[1] = cmul(o[1], wct);                            \
        wct = cmul(wct, P1); o[2] = cmul(o[2], wct);                            \
        wct = cmul(wct, P1); o[3] = cmul(o[3], wct);                            \
        wct = cmul(W0, P2);  o[4] = cmul(o[4], wct);                            \
        wct = cmul(wct, P1); o[5] = cmul(o[5], wct);                            \
        wct = cmul(wct, P1); o[6] = cmul(o[6], wct);                            \
        wct = cmul(wct, P1); o[7] = cmul(o[7], wct);                            \
    }

template <bool CONV, int TMODE>
__global__ __launch_bounds__(256) void kM(const cplx* in, cplx* out, const cplx* __restrict__ tab) {
    __shared__ cplx ld[8 * 545];
    __shared__ cplx tw[TW_SZ];
    const float SGN_F = CONV ? -1.0f : 1.0f;
    const float SGN_B = -SGN_F;
    int row = blockIdx.y;
    int jb = blockIdx.x * 8;
    const cplx* src = in + (size_t)row * NTOT;
    cplx* dst = out + (size_t)row * NTOT;
    const cplx* trow = (TMODE == 3) ? tab : tab + (size_t)row * NTOT;
    int tid = threadIdx.x;
    int jj = tid & 7, n10 = tid >> 3;
    cplx v[16];
    #pragma unroll
    for (int m = 0; m < 16; m++) v[m] = src[(size_t)(n10 + 32 * m) * NN2 + jb + jj];
    init_tw(tw, tid);
    __syncthreads();
    #pragma unroll
    for (int m = 0; m < 8; m++) {
        int b = n10 + 32 * m;
        cplx u = v[m], w = v[m + 8];
        ld[jj * 545 + SK(b)] = cadd(u, w);
        ld[jj * 545 + SK(b + 256)] = cmul(csub(u, w), twget(tw, TWR2, b, SGN_F));
    }
    __syncthreads();
    {
        int r = tid >> 5;
        cplx* rp = ld + r * 545;
        #pragma unroll
        for (int L = 64; L >= 4; L >>= 2) {
            #pragma unroll
            for (int it = 0; it < 4; it++) {
                int idx = (tid & 31) + 32 * it;
                int h = idx >> 6, s = idx & 63;
                int b = s & (L - 1), g = s / L;
                int q0 = h * 256 + g * 4 * L + b;
                cplx y0 = rp[SK(q0)], y1 = rp[SK(q0 + L)], y2 = rp[SK(q0 + 2 * L)], y3 = rp[SK(q0 + 3 * L)];
                r4dif_w(y0, y1, y2, y3, twget(tw, TWOFF(L), b, SGN_F), SGN_F);
                rp[SK(q0)] = y0; rp[SK(q0 + L)] = y1; rp[SK(q0 + 2 * L)] = y2; rp[SK(q0 + 3 * L)] = y3;
            }
            wfence();
        }
        #pragma unroll
        for (int it = 0; it < 4; it++) {
            int idx = (tid & 31) + 32 * it;
            int h = idx >> 6, s = idx & 63;
            int q0 = h * 256 + 4 * s;
            cplx y0 = rp[SK(q0)], y1 = rp[SK(q0 + 1)], y2 = rp[SK(q0 + 2)], y3 = rp[SK(q0 + 3)];
            r4dif0(y0, y1, y2, y3, SGN_F);
            size_t tb = (size_t)(jb + r) * NN1 + q0;
            const cplx* tp = trow + tb;
            cplx t0 = tp[0], t1 = tp[1], t2 = tp[2], t3 = tp[3];
            if (TMODE == 2) { t0 = cmul(t0, t0); t1 = cmul(t1, t1); t2 = cmul(t2, t2); t3 = cmul(t3, t3); }
            y0 = cmul(y0, t0); y1 = cmul(y1, t1); y2 = cmul(y2, t2); y3 = cmul(y3, t3);
            r4dit0(y0, y1, y2, y3, SGN_B);
            rp[SK(q0)] = y0; rp[SK(q0 + 1)] = y1; rp[SK(q0 + 2)] = y2; rp[SK(q0 + 3)] = y3;
        }
        wfence();
        #pragma unroll
        for (int L = 4; L <= 64; L <<= 2) {
            #pragma unroll
            for (int it = 0; it < 4; it++) {
                int idx = (tid & 31) + 32 * it;
                int h = idx >> 6, s = idx & 63;
                int b = s & (L - 1), g = s / L;
                int q0 = h * 256 + g * 4 * L + b;
                cplx y0 = rp[SK(q0)], y1 = rp[SK(q0 + L)], y2 = rp[SK(q0 + 2 * L)], y3 = rp[SK(q0 + 3 * L)];
                r4dit_w(y0, y1, y2, y3, twget(tw, TWOFF(L), b, SGN_B), SGN_B);
                rp[SK(q0)] = y0; rp[SK(q0 + L)] = y1; rp[SK(q0 + 2 * L)] = y2; rp[SK(q0 + 3 * L)] = y3;
            }
            wfence();
        }
    }
    __syncthreads();
    {
        int t = tid;
        cplx r2 = twget(tw, TWR2, t, SGN_B);
        cplx oa[8], ob[8];
        #pragma unroll
        for (int f = 0; f < 8; f++) {
            cplx u = ld[f * 545 + SK(t)];
            cplx w = ld[f * 545 + SK(t + 256)];
            cplx wv = cmul(w, r2);
            oa[f] = cadd(u, wv);
            ob[f] = csub(u, wv);
        }
        int k2b = dig4rev10(jb);
        APPLY_CT(oa, t);
        APPLY_CT(ob, t + 256);
        float4* da = (float4*)(dst + (size_t)t * NN2 + jb);
        da[0] = make_float4(oa[0].x, oa[0].y, oa[1].x, oa[1].y);
        da[1] = make_float4(oa[2].x, oa[2].y, oa[3].x, oa[3].y);
        da[2] = make_float4(oa[4].x, oa[4].y, oa[5].x, oa[5].y);
        da[3] = make_float4(oa[6].x, oa[6].y, oa[7].x, oa[7].y);
        float4* db = (float4*)(dst + (size_t)(t + 256) * NN2 + jb);
        db[0] = make_float4(ob[0].x, ob[0].y, ob[1].x, ob[1].y);
        db[1] = make_float4(ob[2].x, ob[2].y, ob[3].x, ob[3].y);
        db[2] = make_float4(ob[4].x, ob[4].y, ob[5].x, ob[5].y);
        db[3] = make_float4(ob[6].x, ob[6].y, ob[7].x, ob[7].y);
    }
}

// ---------------------------------------------------------------------------
// kB2T (plain, tail only): Zt[row][n1*1024 + j] -> time xT[n1*1024+n2]
// ---------------------------------------------------------------------------
__global__ __launch_bounds__(256) void kB2T(const cplx* __restrict__ in, cplx* __restrict__ out) {
    __shared__ cplx ld[1024 + 64];
    __shared__ cplx tw[TW_SZ];
    int row = blockIdx.y;
    int n1 = blockIdx.x;
    int tid = threadIdx.x;
    size_t base = (size_t)row * NTOT + (size_t)n1 * NN2;
    init_tw(tw, tid);
    __syncthreads();
    cplx y[4];
    fft_j2n2<-1>(in + base, y, ld, tw, tid);
    #pragma unroll
    for (int q = 0; q < 4; q++) out[base + tid + q * 256] = y[q];
}

// ---------------------------------------------------------------------------
// kNL: fused nonlinear kernel. 16 inverse conv FFTs (Z rows: 0-9 = W of the
//   10 unique pairs, 10-15 = U of the 6 off-diag pairs, used conjugated with
//   swapped (r,s)) + S-contraction + Kerr, then 4 forward FFTs -> Tbout.
// ---------------------------------------------------------------------------
__global__ __launch_bounds__(256) void kNL(const cplx* __restrict__ Zin, const cplx* __restrict__ A,
                                           const float* __restrict__ Sg, cplx* __restrict__ Tbout) {
    __shared__ cplx ld0[1024 + 64];
    __shared__ cplx ld1[1024 + 64];
    __shared__ cplx tw[TW_SZ];
    __shared__ float Ssh[256];
    int n1 = blockIdx.x, tid = threadIdx.x;
    Ssh[tid] = Sg[tid];
    init_tw(tw, tid);
    size_t base = (size_t)n1 * NN2;
    size_t tb = base + tid;
    cplx am[4][4];
    #pragma unroll
    for (int m = 0; m < 4; m++)
        #pragma unroll
        for (int q = 0; q < 4; q++) am[m][q] = A[(size_t)m * NTOT + tb + q * 256];
    cplx acc[4][4];
    #pragma unroll
    for (int p = 0; p < 4; p++)
        #pragma unroll
        for (int q = 0; q < 4; q++) acc[p][q] = make_float2(0.f, 0.f);
    __syncthreads();  // tw/Ssh ready
    // packed (r,s) maps: rows 0-9 = {(0,0),(1,1),(2,2),(3,3),(0,1),(0,2),(0,3),
    // (1,2),(1,3),(2,3)}; rows 10-15 = swapped pairs {(1,0),(2,0),(3,0),(2,1),(3,1),(3,2)}
    const unsigned RP = (0u << 0) | (1u << 2) | (2u << 4) | (3u << 6) | (0u << 8) | (0u << 10) | (0u << 12) |
                        (1u << 14) | (1u << 16) | (2u << 18) | (1u << 20) | (2u << 22) | (3u << 24) |
                        (2u << 26) | (3u << 28) | (3u << 30);
    const unsigned SP = (0u << 0) | (1u << 2) | (2u << 4) | (3u << 6) | (1u << 8) | (2u << 10) | (3u << 12) |
                        (2u << 14) | (3u << 16) | (3u << 18) | (0u << 20) | (0u << 22) | (0u << 24) |
                        (1u << 26) | (1u << 28) | (2u << 30);
    for (int rowi = 0; rowi < 16; rowi++) {
        cplx* buf = (rowi & 1) ? ld1 : ld0;
        cplx tc[4];
        fft_j2n2<1>(Zin + (size_t)rowi * NTOT + base, tc, buf, tw, tid);
        int r = (int)((RP >> (2 * rowi)) & 3u);
        int s = (int)((SP >> (2 * rowi)) & 3u);
        float csg = (rowi >= 10) ? -1.0f : 1.0f;  // conj(tc) for swapped rows
        #pragma unroll
        for (int q = 0; q < 4; q++) {
            cplx tcq = make_float2(tc[q].x, csg * tc[q].y);
            #pragma unroll
            for (int p = 0; p < 4; p++) {
                float c0 = Ssh[((p * 4 + 0) * 4 + r) * 4 + s];
                float c1 = Ssh[((p * 4 + 1) * 4 + r) * 4 + s];
                float c2 = Ssh[((p * 4 + 2) * 4 + r) * 4 + s];
                float c3 = Ssh[((p * 4 + 3) * 4 + r) * 4 + s];
                cplx c;
                c.x = c0 * am[0][q].x + c1 * am[1][q].x + c2 * am[2][q].x + c3 * am[3][q].x;
                c.y = c0 * am[0][q].y + c1 * am[1][q].y + c2 * am[2][q].y + c3 * am[3][q].y;
                acc[p][q] = cadd(acc[p][q], cmul(c, tcq));
            }
        }
    }
    // Kerr + combine (acc becomes S_total)
    #pragma unroll
    for (int q = 0; q < 4; q++) {
        cplx pp[4][4];
        #pragma unroll
        for (int r = 0; r < 4; r++)
            #pragma unroll
            for (int s = 0; s < 4; s++) pp[r][s] = cmul(am[r][q], conjc(am[s][q]));
        #pragma unroll
        for (int p = 0; p < 4; p++) {
            cplx kc = make_float2(0.f, 0.f);
            #pragma unroll
            for (int m = 0; m < 4; m++) {
                cplx g = make_float2(0.f, 0.f);
                #pragma unroll
                for (int r = 0; r < 4; r++)
                    #pragma unroll
                    for (int s = 0; s < 4; s++) {
                        float coef = Ssh[((p * 4 + m) * 4 + r) * 4 + s];
                        g.x += coef * pp[r][s].x;
                        g.y += coef * pp[r][s].y;
                    }
                kc = cadd(kc, cmul(g, am[m][q]));
            }
            acc[p][q] = cadd(cscale(kc, 1.0f - FRv), cscale(acc[p][q], FRv));
        }
    }
    cplx w0 = expi_pi((float)(n1 * dig4rev10(4 * tid)) * (2.0f / (float)NTOT), 1.0f);
    cplx dlt = expi_pi((float)n1 * (1.0f / 1024.0f), 1.0f);
    #pragma unroll
    for (int p = 0; p < 4; p++) {
        cplx* buf = (p & 1) ? ld1 : ld0;
        cplx y[4] = {acc[p][0], acc[p][1], acc[p][2], acc[p][3]};
        fft_n22j<true>(y, buf, tw, tid, w0, dlt, Tbout + (size_t)p * NTOT + base);
    }
}

// ---------------------------------------------------------------------------
// kRK<STAGE>: knl spectrum Tbin -> time (fft over j) + RK4 update.
//   STAGE 1-3: 10 unique TFORM rows -> ZOut[0..9].
// ---------------------------------------------------------------------------
template <int STAGE>
__global__ __launch_bounds__(256) void kRK(const cplx* Tbin, const cplx* __restrict__ fP,
                                           cplx* __restrict__ kaccP, cplx* __restrict__ AtmpP,
                                           cplx* ZOut) {
    __shared__ cplx ld0[1024 + 64];
    __shared__ cplx ld1[1024 + 64];
    __shared__ cplx tw[TW_SZ];
    int n1 = blockIdx.x, tid = threadIdx.x;
    init_tw(tw, tid);
    __syncthreads();
    size_t base = (size_t)n1 * NN2;
    cplx an[4][4];
    #pragma unroll
    for (int p = 0; p < 4; p++) {
        cplx* buf = (p & 1) ? ld1 : ld0;
        cplx y[4];
        fft_j2n2<-1>(Tbin + (size_t)p * NTOT + base, y, buf, tw, tid);
        #pragma unroll
        for (int q = 0; q < 4; q++) {
            size_t off = (size_t)p * NTOT + base + tid + q * 256;
            cplx v = y[q];
            if (STAGE == 1) {
                kaccP[off] = v;
                an[p][q] = cadd(fP[off], cscale(v, 0.5f));
                AtmpP[off] = an[p][q];
            } else if (STAGE == 2) {
                kaccP[off] = cadd(kaccP[off], cscale(v, 2.0f));
                an[p][q] = cadd(fP[off], cscale(v, 0.5f));
                AtmpP[off] = an[p][q];
            } else if (STAGE == 3) {
                kaccP[off] = cadd(kaccP[off], cscale(v, 2.0f));
                an[p][q] = cadd(fP[off], v);
                AtmpP[off] = an[p][q];
            } else {
                an[p][q] = cadd(fP[off], cscale(cadd(kaccP[off], v), 1.0f / 6.0f));
            }
        }
    }
    const float SGN = (STAGE == 4) ? 1.0f : -1.0f;
    cplx w0 = expi_pi((float)(n1 * dig4rev10(4 * tid)) * (2.0f / (float)NTOT), SGN);
    cplx dlt = expi_pi((float)n1 * (1.0f / 1024.0f), SGN);
    if (STAGE <= 3) {
        const int R10[10] = {0, 1, 2, 3, 0, 0, 0, 1, 1, 2};
        const int S10[10] = {0, 1, 2, 3, 1, 2, 3, 2, 3, 3};
        #pragma unroll
        for (int rw = 0; rw < 10; rw++) {
            cplx* buf = (rw & 1) ? ld1 : ld0;
            int r = R10[rw], s = S10[rw];
            cplx y[4];
            #pragma unroll
            for (int q = 0; q < 4; q++) y[q] = cmul(an[r][q], conjc(an[s][q]));
            fft_n22j<false>(y, buf, tw, tid, w0, dlt, ZOut + (size_t)rw * NTOT + base);
        }
    } else {
        #pragma unroll
        for (int p = 0; p < 4; p++) {
            cplx* buf = (p & 1) ? ld1 : ld0;
            cplx y[4] = {an[p][0], an[p][1], an[p][2], an[p][3]};
            fft_n22j<true>(y, buf, tw, tid, w0, dlt, ZOut + (size_t)p * NTOT + base);
        }
    }
}

// ---------------------------------------------------------------------------
// kBD: boundary tail. Tbin -> f (stored) + 10 unique TFORM rows -> ZOut[0..9].
// ---------------------------------------------------------------------------
__global__ __launch_bounds__(256) void kBD(const cplx* __restrict__ Tbin, cplx* __restrict__ fP,
                                           cplx* __restrict__ ZOut) {
    __shared__ cplx ld0[1024 + 64];
    __shared__ cplx ld1[1024 + 64];
    __shared__ cplx tw[TW_SZ];
    int n1 = blockIdx.x, tid = threadIdx.x;
    init_tw(tw, tid);
    __syncthreads();
    size_t base = (size_t)n1 * NN2;
    cplx an[4][4];
    #pragma unroll
    for (int p = 0; p < 4; p++) {
        cplx* buf = (p & 1) ? ld1 : ld0;
        cplx y[4];
        fft_j2n2<-1>(Tbin + (size_t)p * NTOT + base, y, buf, tw, tid);
        #pragma unroll
        for (int q = 0; q < 4; q++) {
            size_t off = (size_t)p * NTOT + base + tid + q * 256;
            an[p][q] = y[q];
            fP[off] = y[q];
        }
    }
    cplx w0 = expi_pi((float)(n1 * dig4rev10(4 * tid)) * (2.0f / (float)NTOT), -1.0f);
    cplx dlt = expi_pi((float)n1 * (1.0f / 1024.0f), -1.0f);
    const int R10[10] = {0, 1, 2, 3, 0, 0, 0, 1, 1, 2};
    const int S10[10] = {0, 1, 2, 3, 1, 2, 3, 2, 3, 3};
    #pragma unroll
    for (int rw = 0; rw < 10; rw++) {
        cplx* buf = (rw & 1) ? ld1 : ld0;
        int r = R10[rw], s = S10[rw];
        cplx y[4];
        #pragma unroll
        for (int q = 0; q < 4; q++) y[q] = cmul(an[r][q], conjc(an[s][q]));
        fft_n22j<false>(y, buf, tw, tid, w0, dlt, ZOut + (size_t)rw * NTOT + base);
    }
}

// ---------------------------------------------------------------------------
// Pointwise kernels
// ---------------------------------------------------------------------------
__global__ __launch_bounds__(256) void k_tables(const float* __restrict__ D_re, const float* __restrict__ D_im,
                                                const float* __restrict__ hrw_re, const float* __restrict__ hrw_im,
                                                const float* __restrict__ omega,
                                                cplx* __restrict__ lin, cplx* __restrict__ pref,
                                                cplx* __restrict__ hrwc, cplx* __restrict__ gtab) {
    int k = blockIdx.x * 256 + threadIdx.x;
    if (k >= NTOT) return;
    int k2 = k & (NN2 - 1), k1 = k >> 10;
    int j = dig4rev10(k2), i = islot_512(k1);
    int s2 = j * NN1 + i;
    float om = omega[k];
    pref[s2] = make_float2(0.0f, GAMMAv * DZv * (1.0f + om / OMEGA0v));
    hrwc[s2] = make_float2(hrw_re[k] * DTv, -hrw_im[k] * DTv);
    int kr = (NTOT - k) & (NTOT - 1);
    // g[k] = conj(hrwc[N-k]) = hrw[N-k] * DT
    gtab[s2] = make_float2(hrw_re[kr] * DTv, hrw_im[kr] * DTv);
    for (int p = 0; p < PM; p++) {
        float dr = D_re[(size_t)p * NTOT + k], di = D_im[(size_t)p * NTOT + k];
        float amp = expf(-0.5f * DZv * di);
        float s, c;
        sincosf(0.5f * DZv * dr, &s, &c);
        lin[(size_t)p * NTOT + s2] = make_float2(amp * c, amp * s);
    }
}

__global__ void k_in(const float* __restrict__ Are, const float* __restrict__ Aim, cplx* __restrict__ f) {
    __shared__ cplx t[32][33];
    int p = blockIdx.z;
    int n1b = blockIdx.x * 32, n2b = blockIdx.y * 32;
    int tx = threadIdx.x, ty = threadIdx.y;
    const float* ar = Are + (size_t)p * NTOT;
    const float* ai = Aim + (size_t)p * NTOT;
    for (int yy = ty; yy < 32; yy += 8) {
        size_t idx = (size_t)(n2b + yy) * NN1 + (n1b + tx);
        t[yy][tx] = make_float2(ar[idx], ai[idx]);
    }
    __syncthreads();
    cplx* dst = f + (size_t)p * NTOT;
    for (int yy = ty; yy < 32; yy += 8) {
        dst[(size_t)(n1b + yy) * NN2 + (n2b + tx)] = t[tx][yy];
    }
}

__global__ void k_out(const cplx* __restrict__ fin, float* __restrict__ out) {
    __shared__ cplx t[32][33];
    int p = blockIdx.z;
    int n1b = blockIdx.x * 32, n2b = blockIdx.y * 32;
    int tx = threadIdx.x, ty = threadIdx.y;
    const cplx* src = fin + (size_t)p * NTOT;
    for (int yy = ty; yy < 32; yy += 8) {
        t[yy][tx] = src[(size_t)(n1b + yy) * NN2 + (n2b + tx)];
    }
    __syncthreads();
    float* outr = out + (size_t)p * NTOT;
    float* outi = out + (size_t)(PM + p) * NTOT;
    for (int yy = ty; yy < 32; yy += 8) {
        cplx v = t[tx][yy];
        size_t idx = (size_t)(n2b + yy) * NN1 + (n1b + tx);
        outr[idx] = v.x;
        outi[idx] = v.y;
    }
}

// ---------------------------------------------------------------------------
extern "C" void kernel_launch(void* const* d_in, const int* in_sizes, int n_in,
                              void* d_out, int out_size, void* d_ws, size_t ws_size,
                              hipStream_t stream) {
    const float* Are = (const float*)d_in[0];
    const float* Aim = (const float*)d_in[1];
    const float* S = (const float*)d_in[2];
    const float* Dre = (const float*)d_in[3];
    const float* Dim = (const float*)d_in[4];
    const float* hre = (const float*)d_in[5];
    const float* him = (const float*)d_in[6];
    const float* omega = (const float*)d_in[7];

    const size_t ROW = (size_t)NTOT;
    // ws rows: f(4) Atmp(4) kacc(4) lin(4) pref(1) hrwc(1) g(1) Tb(4) Z(16) = 39
    if (ws_size < 39ULL * ROW * sizeof(cplx)) return;
    cplx* f = (cplx*)d_ws;
    cplx* Atmp = f + 4 * ROW;
    cplx* kacc = Atmp + 4 * ROW;
    cplx* lin = kacc + 4 * ROW;
    cplx* pref = lin + 4 * ROW;
    cplx* hrwc = pref + 1 * ROW;
    cplx* gtab = hrwc + 1 * ROW;
    cplx* Tb = gtab + 1 * ROW;
    cplx* Z = Tb + 4 * ROW;

    dim3 b256(256);
    dim3 gT(16, 32, 4), bT(32, 8);
    dim3 gPW1(NTOT / 256);

    k_tables<<<gPW1, b256, 0, stream>>>(Dre, Dim, hre, him, omega, lin, pref, hrwc, gtab);
    k_in<<<gT, bT, 0, stream>>>(Are, Aim, f);
    // Tb = ifft-spectrum of A0  (boundary input)
    kA1<true><<<dim3(512, 4), b256, 0, stream>>>(f, Tb);

    for (int step = 0; step < NZ_STEPS; step++) {
        if (step == 0)
            kM<false, 1><<<dim3(128, 4), b256, 0, stream>>>(Tb, Tb, lin);
        else
            kM<false, 2><<<dim3(128, 4), b256, 0, stream>>>(Tb, Tb, lin);
        kBD<<<dim3(512), b256, 0, stream>>>(Tb, f, Z);
        for (int st = 1; st <= 4; st++) {
            const cplx* Aarg = (st == 1) ? f : Atmp;
            // conv: U rows first (reads Z rows 4..9 before W pass overwrites)
            kM<true, 3><<<dim3(128, 6), b256, 0, stream>>>(Z + 4 * ROW, Z + 10 * ROW, gtab);
            kM<true, 3><<<dim3(128, 10), b256, 0, stream>>>(Z, Z, hrwc);
            kNL<<<dim3(512), b256, 0, stream>>>(Z, Aarg, S, Tb);
            kM<false, 3><<<dim3(128, 4), b256, 0, stream>>>(Tb, Tb, pref);
            if (st == 1)
                kRK<1><<<dim3(512), b256, 0, stream>>>(Tb, f, kacc, Atmp, Z);
            else if (st == 2)
                kRK<2><<<dim3(512), b256, 0, stream>>>(Tb, f, kacc, Atmp, Z);
            else if (st == 3)
                kRK<3><<<dim3(512), b256, 0, stream>>>(Tb, f, kacc, Atmp, Z);
            else
                kRK<4><<<dim3(512), b256, 0, stream>>>(Tb, f, kacc, nullptr, Tb);
        }
    }
    // tail: out = fft(lin * ifft(f_final)) -> natural layout
    kM<false, 1><<<dim3(128, 4), b256, 0, stream>>>(Tb, Tb, lin);
    kB2T<<<dim3(512, 4), b256, 0, stream>>>(Tb, Atmp);
    k_out<<<gT, bT, 0, stream>>>(Atmp, (float*)d_out);
}

// Round 19
// 8228.041 us; speedup vs baseline: 1.0211x; 1.0211x over previous
//
#include <hip/hip_runtime.h>
#include <math.h>

// Problem constants (match reference setup_inputs)
#define NTOT (1 << 19)   // 524288
#define NN1 512          // n1: fast time index,  k1: slow freq index
#define NN2 1024         // n2: slow time index,  k2: fast freq index
#define PM 4
#define NZ_STEPS 10

static const float DZv = 1.0e-3f;
static const float DTv = 0.01f;
static const float GAMMAv = 1.0e-3f;
static const float FRv = 0.18f;
static const float OMEGA0v = 1830.0f;

typedef float2 cplx;
__device__ inline cplx cmul(cplx a, cplx b) { return make_float2(a.x * b.x - a.y * b.y, a.x * b.y + a.y * b.x); }
__device__ inline cplx cadd(cplx a, cplx b) { return make_float2(a.x + b.x, a.y + b.y); }
__device__ inline cplx csub(cplx a, cplx b) { return make_float2(a.x - b.x, a.y - b.y); }
__device__ inline cplx cscale(cplx a, float s) { return make_float2(a.x * s, a.y * s); }
__device__ inline cplx conjc(cplx a) { return make_float2(a.x, -a.y); }
// e^{i * sgn * pi * a}
__device__ inline cplx expi_pi(float a, float sgn) {
    float s, c;
    sincospif(a, &s, &c);
    return make_float2(c, sgn * s);
}
// base-4 digit reversals (involutions)
__device__ inline int dig4rev10(int j) {
    return ((j & 3) << 8) | (((j >> 2) & 3) << 6) | (((j >> 4) & 3) << 4) | (((j >> 6) & 3) << 2) | ((j >> 8) & 3);
}
__device__ inline int b4rev8(int t) {
    return ((t & 3) << 6) | (((t >> 2) & 3) << 4) | (((t >> 4) & 3) << 2) | ((t >> 6) & 3);
}
__device__ inline int islot_512(int k1) { return ((k1 & 1) << 8) | b4rev8(k1 >> 1); }  // k1 -> slot

#define SK(q) ((q) + ((q) >> 4))   // LDS skew (float2 units)

// Wave-local fence: intra-wave LDS RAW needs only compile-time ordering.
__device__ inline void wfence() {
    asm volatile("" ::: "memory");
    __builtin_amdgcn_wave_barrier();
    asm volatile("" ::: "memory");
}

// ---- twiddle tables: T4[4] T16[16] T64[64] T256[256] R2[256] ----
#define TW_SZ 596
#define TWOFF(L) ((L) == 4 ? 0 : (L) == 16 ? 4 : (L) == 64 ? 20 : 84)
#define TWR2 340
__device__ inline void init_tw(cplx* tw, int tid) {
    for (int idx = tid; idx < TW_SZ; idx += 256) {
        float a;
        if (idx < 4) a = (float)idx * (0.5f / 4.0f);
        else if (idx < 20) a = (float)(idx - 4) * (0.5f / 16.0f);
        else if (idx < 84) a = (float)(idx - 20) * (0.5f / 64.0f);
        else if (idx < 340) a = (float)(idx - 84) * (0.5f / 256.0f);
        else a = (float)(idx - 340) * (1.0f / 256.0f);
        float s, c;
        sincospif(a, &s, &c);
        tw[idx] = make_float2(c, s);
    }
}
__device__ inline cplx twget(const cplx* tw, int off, int b, float SGN) {
    cplx t = tw[off + b];
    return make_float2(t.x, SGN * t.y);
}

// radix-4 butterflies with supplied twiddle w1 (w2=w1^2, w3=w1^3 derived)
__device__ inline void r4dif_w(cplx& x0, cplx& x1, cplx& x2, cplx& x3, cplx w1, float SGN) {
    cplx t0 = cadd(x0, x2), t1 = cadd(x1, x3), t2 = csub(x0, x2), t3 = csub(x1, x3);
    cplx ct3 = make_float2(-SGN * t3.y, SGN * t3.x);
    cplx w2 = cmul(w1, w1), w3 = cmul(w2, w1);
    x0 = cadd(t0, t1);
    x1 = cmul(cadd(t2, ct3), w1);
    x2 = cmul(csub(t0, t1), w2);
    x3 = cmul(csub(t2, ct3), w3);
}
__device__ inline void r4dif0(cplx& x0, cplx& x1, cplx& x2, cplx& x3, float SGN) {
    cplx t0 = cadd(x0, x2), t1 = cadd(x1, x3), t2 = csub(x0, x2), t3 = csub(x1, x3);
    cplx ct3 = make_float2(-SGN * t3.y, SGN * t3.x);
    x0 = cadd(t0, t1); x1 = cadd(t2, ct3); x2 = csub(t0, t1); x3 = csub(t2, ct3);
}
__device__ inline void r4dit_w(cplx& x0, cplx& x1, cplx& x2, cplx& x3, cplx w1, float SGN) {
    cplx w2 = cmul(w1, w1), w3 = cmul(w2, w1);
    cplx z1 = cmul(x1, w1), z2 = cmul(x2, w2), z3 = cmul(x3, w3);
    cplx t0 = cadd(x0, z2), t1 = cadd(z1, z3), t2 = csub(x0, z2), t3 = csub(z1, z3);
    cplx ct3 = make_float2(-SGN * t3.y, SGN * t3.x);
    x0 = cadd(t0, t1); x1 = cadd(t2, ct3); x2 = csub(t0, t1); x3 = csub(t2, ct3);
}
__device__ inline void r4dit0(cplx& x0, cplx& x1, cplx& x2, cplx& x3, float SGN) {
    cplx t0 = cadd(x0, x2), t1 = cadd(x1, x3), t2 = csub(x0, x2), t3 = csub(x1, x3);
    cplx ct3 = make_float2(-SGN * t3.y, SGN * t3.x);
    x0 = cadd(t0, t1); x1 = cadd(t2, ct3); x2 = csub(t0, t1); x3 = csub(t2, ct3);
}

// ---------------------------------------------------------------------------
// FFT line helpers (256-thread block, one 1024-pt line).
// ---------------------------------------------------------------------------
template <int ISGN>
__device__ inline void fft_j2n2(const cplx* gsrc, cplx* y, cplx* ld, const cplx* tw, int tid) {
    const float SGN = (float)ISGN;
    const float4* s4 = (const float4*)gsrc;
    float4 va = s4[2 * tid], vb = s4[2 * tid + 1];
    cplx y0 = make_float2(va.x, va.y), y1 = make_float2(va.z, va.w);
    cplx y2 = make_float2(vb.x, vb.y), y3 = make_float2(vb.z, vb.w);
    r4dit0(y0, y1, y2, y3, SGN);
    int q0 = 4 * tid;
    ld[SK(q0)] = y0; ld[SK(q0 + 1)] = y1; ld[SK(q0 + 2)] = y2; ld[SK(q0 + 3)] = y3;
    wfence();
    #pragma unroll
    for (int L = 4; L <= 64; L <<= 2) {
        int b = tid & (L - 1), g = tid / L;
        int p0 = g * 4 * L + b;
        cplx z0 = ld[SK(p0)], z1 = ld[SK(p0 + L)], z2 = ld[SK(p0 + 2 * L)], z3 = ld[SK(p0 + 3 * L)];
        r4dit_w(z0, z1, z2, z3, twget(tw, TWOFF(L), b, SGN), SGN);
        ld[SK(p0)] = z0; ld[SK(p0 + L)] = z1; ld[SK(p0 + 2 * L)] = z2; ld[SK(p0 + 3 * L)] = z3;
        if (L == 64) __syncthreads();  // next stage (L=256) reads cross-wave
        else wfence();
    }
    {
        int b = tid;
        cplx z0 = ld[SK(b)], z1 = ld[SK(b + 256)], z2 = ld[SK(b + 512)], z3 = ld[SK(b + 768)];
        r4dit_w(z0, z1, z2, z3, twget(tw, 84, b, SGN), SGN);
        y[0] = z0; y[1] = z1; y[2] = z2; y[3] = z3;
    }
}

// w0 = expi_pi(n1*dig4rev10(4*tid)*2/NTOT, SGN), dlt = expi_pi(n1/1024, SGN)
template <bool INV>
__device__ inline void fft_n22j(cplx* y, cplx* ld, const cplx* tw, int tid, cplx w0, cplx dlt, cplx* gdst) {
    const float SGN = INV ? 1.0f : -1.0f;
    r4dif_w(y[0], y[1], y[2], y[3], twget(tw, 84, tid, SGN), SGN);
    ld[SK(tid)] = y[0]; ld[SK(tid + 256)] = y[1]; ld[SK(tid + 512)] = y[2]; ld[SK(tid + 768)] = y[3];
    __syncthreads();  // scattered write, cross-wave readers below
    #pragma unroll
    for (int L = 64; L >= 4; L >>= 2) {
        int b = tid & (L - 1), g = tid / L;
        int p0 = g * 4 * L + b;
        cplx z0 = ld[SK(p0)], z1 = ld[SK(p0 + L)], z2 = ld[SK(p0 + 2 * L)], z3 = ld[SK(p0 + 3 * L)];
        r4dif_w(z0, z1, z2, z3, twget(tw, TWOFF(L), b, SGN), SGN);
        ld[SK(p0)] = z0; ld[SK(p0 + L)] = z1; ld[SK(p0 + 2 * L)] = z2; ld[SK(p0 + 3 * L)] = z3;
        wfence();  // L=64,16,4 and final read are wave-segment-local
    }
    {
        int p0 = 4 * tid;
        cplx z0 = ld[SK(p0)], z1 = ld[SK(p0 + 1)], z2 = ld[SK(p0 + 2)], z3 = ld[SK(p0 + 3)];
        r4dif0(z0, z1, z2, z3, SGN);
        cplx w = INV ? cscale(w0, 1.0f / (float)NTOT) : w0;
        cplx o0 = cmul(z0, w); w = cmul(w, dlt);
        cplx o1 = cmul(z1, w); w = cmul(w, dlt);
        cplx o2 = cmul(z2, w); w = cmul(w, dlt);
        cplx o3 = cmul(z3, w);
        float4* d4 = (float4*)(gdst + p0);
        d4[0] = make_float4(o0.x, o0.y, o1.x, o1.y);
        d4[1] = make_float4(o2.x, o2.y, o3.x, o3.y);
    }
}

// ---------------------------------------------------------------------------
// kA1: time layout xT[n1*1024+n2] -> Z[n1*1024+j] (prologue only)
// ---------------------------------------------------------------------------
template <bool INV>
__global__ __launch_bounds__(256) void kA1(const cplx* __restrict__ in, cplx* __restrict__ out) {
    __shared__ cplx ld[1024 + 64];
    __shared__ cplx tw[TW_SZ];
    int row = blockIdx.y;
    int n1 = blockIdx.x;
    int tid = threadIdx.x;
    const cplx* src = in + (size_t)row * NTOT;
    cplx* dst = out + (size_t)row * NTOT;
    size_t base = (size_t)n1 * NN2;
    cplx y[4];
    y[0] = src[base + tid];
    y[1] = src[base + tid + 256];
    y[2] = src[base + tid + 512];
    y[3] = src[base + tid + 768];
    init_tw(tw, tid);
    __syncthreads();
    const float SGN = INV ? 1.0f : -1.0f;
    cplx w0 = expi_pi((float)(n1 * dig4rev10(4 * tid)) * (2.0f / (float)NTOT), SGN);
    cplx dlt = expi_pi((float)n1 * (1.0f / 1024.0f), SGN);
    fft_n22j<INV>(y, ld, tw, tid, w0, dlt, dst + base);
}

// ---------------------------------------------------------------------------
// kM: FUSED middle kernel (in-place safe). Per 8 j-lines: 512-pt FFT over n1
//     (dir F), table multiply, 512-pt FFT back (dir B=-F), cross twiddle,
//     TRANSPOSED store to out[n1*1024 + j].
//   WAVE-LOCAL remap: row r = tid>>5 (32 threads/row); all butterfly stages
//   + pivot are wave-local (wfence only).
// ---------------------------------------------------------------------------
#define APPLY_CT(o, n1v)                                                        \
    {                                                                           \
        cplx W0 = expi_pi((float)((n1v) * k2b) * (2.0f / (float)NTOT), SGN_B);  \
        if (CONV) W0 = cscale(W0, 1.0f / (float)NTOT);                          \
        cplx P1 = expi_pi((float)(n1v) * (1.0f / 1024.0f), SGN_B);              \
        cplx P2 = expi_pi((float)(n1v) * (1.0f / 4096.0f), SGN_B);              \
        cplx wct = W0;                                                          \
        o[0] = cmul(o[0], wct);                                                 \
        wct = cmul(wct, P1); o[1] = cmul(o[1], wct);                            \
        wct = cmul(wct, P1); o[2] = cmul(o[2], wct);                            \
        wct = cmul(wct, P1); o[3] = cmul(o[3], wct);                            \
        wct = cmul(W0, P2);  o[4] = cmul(o[4], wct);                            \
        wct = cmul(wct, P1); o[5] = cmul(o[5], wct);                            \
        wct = cmul(wct, P1); o[6] = cmul(o[6], wct);                            \
        wct = cmul(wct, P1); o[7] = cmul(o[7], wct);                            \
    }

template <bool CONV, int TMODE>
__global__ __launch_bounds__(256) void kM(const cplx* in, cplx* out, const cplx* __restrict__ tab) {
    __shared__ cplx ld[8 * 545];
    __shared__ cplx tw[TW_SZ];
    const float SGN_F = CONV ? -1.0f : 1.0f;
    const float SGN_B = -SGN_F;
    int row = blockIdx.y;
    int jb = blockIdx.x * 8;
    const cplx* src = in + (size_t)row * NTOT;
    cplx* dst = out + (size_t)row * NTOT;
    const cplx* trow = (TMODE == 3) ? tab : tab + (size_t)row * NTOT;
    int tid = threadIdx.x;
    int jj = tid & 7, n10 = tid >> 3;
    cplx v[16];
    #pragma unroll
    for (int m = 0; m < 16; m++) v[m] = src[(size_t)(n10 + 32 * m) * NN2 + jb + jj];
    init_tw(tw, tid);
    __syncthreads();
    #pragma unroll
    for (int m = 0; m < 8; m++) {
        int b = n10 + 32 * m;
        cplx u = v[m], w = v[m + 8];
        ld[jj * 545 + SK(b)] = cadd(u, w);
        ld[jj * 545 + SK(b + 256)] = cmul(csub(u, w), twget(tw, TWR2, b, SGN_F));
    }
    __syncthreads();  // scatter was cross-wave vs row ownership below
    // ---- forward radix-4 stages (wave-local rows: r = tid>>5) ----
    {
        int r = tid >> 5;
        cplx* rp = ld + r * 545;
        #pragma unroll
        for (int L = 64; L >= 4; L >>= 2) {
            #pragma unroll
            for (int it = 0; it < 4; it++) {
                int idx = (tid & 31) + 32 * it;  // 0..127 per row
                int h = idx >> 6, s = idx & 63;
                int b = s & (L - 1), g = s / L;
                int q0 = h * 256 + g * 4 * L + b;
                cplx y0 = rp[SK(q0)], y1 = rp[SK(q0 + L)], y2 = rp[SK(q0 + 2 * L)], y3 = rp[SK(q0 + 3 * L)];
                r4dif_w(y0, y1, y2, y3, twget(tw, TWOFF(L), b, SGN_F), SGN_F);
                rp[SK(q0)] = y0; rp[SK(q0 + L)] = y1; rp[SK(q0 + 2 * L)] = y2; rp[SK(q0 + 3 * L)] = y3;
            }
            wfence();
        }
        // ---- pivot: DIF L=1 + table multiply + DIT L=1 (row-local) ----
        #pragma unroll
        for (int it = 0; it < 4; it++) {
            int idx = (tid & 31) + 32 * it;
            int h = idx >> 6, s = idx & 63;
            int q0 = h * 256 + 4 * s;
            cplx y0 = rp[SK(q0)], y1 = rp[SK(q0 + 1)], y2 = rp[SK(q0 + 2)], y3 = rp[SK(q0 + 3)];
            r4dif0(y0, y1, y2, y3, SGN_F);
            size_t tb = (size_t)(jb + r) * NN1 + q0;
            const cplx* tp = trow + tb;
            cplx t0 = tp[0], t1 = tp[1], t2 = tp[2], t3 = tp[3];
            if (TMODE == 2) { t0 = cmul(t0, t0); t1 = cmul(t1, t1); t2 = cmul(t2, t2); t3 = cmul(t3, t3); }
            y0 = cmul(y0, t0); y1 = cmul(y1, t1); y2 = cmul(y2, t2); y3 = cmul(y3, t3);
            r4dit0(y0, y1, y2, y3, SGN_B);
            rp[SK(q0)] = y0; rp[SK(q0 + 1)] = y1; rp[SK(q0 + 2)] = y2; rp[SK(q0 + 3)] = y3;
        }
        wfence();
        // ---- inverse radix-4 stages (row-local) ----
        #pragma unroll
        for (int L = 4; L <= 64; L <<= 2) {
            #pragma unroll
            for (int it = 0; it < 4; it++) {
                int idx = (tid & 31) + 32 * it;
                int h = idx >> 6, s = idx & 63;
                int b = s & (L - 1), g = s / L;
                int q0 = h * 256 + g * 4 * L + b;
                cplx y0 = rp[SK(q0)], y1 = rp[SK(q0 + L)], y2 = rp[SK(q0 + 2 * L)], y3 = rp[SK(q0 + 3 * L)];
                r4dit_w(y0, y1, y2, y3, twget(tw, TWOFF(L), b, SGN_B), SGN_B);
                rp[SK(q0)] = y0; rp[SK(q0 + L)] = y1; rp[SK(q0 + 2 * L)] = y2; rp[SK(q0 + 3 * L)] = y3;
            }
            wfence();
        }
    }
    __syncthreads();  // final combine reads all rows (cross-wave)
    {
        int t = tid;
        cplx r2 = twget(tw, TWR2, t, SGN_B);
        cplx oa[8], ob[8];
        #pragma unroll
        for (int f = 0; f < 8; f++) {
            cplx u = ld[f * 545 + SK(t)];
            cplx w = ld[f * 545 + SK(t + 256)];
            cplx wv = cmul(w, r2);
            oa[f] = cadd(u, wv);
            ob[f] = csub(u, wv);
        }
        int k2b = dig4rev10(jb);
        APPLY_CT(oa, t);
        APPLY_CT(ob, t + 256);
        float4* da = (float4*)(dst + (size_t)t * NN2 + jb);
        da[0] = make_float4(oa[0].x, oa[0].y, oa[1].x, oa[1].y);
        da[1] = make_float4(oa[2].x, oa[2].y, oa[3].x, oa[3].y);
        da[2] = make_float4(oa[4].x, oa[4].y, oa[5].x, oa[5].y);
        da[3] = make_float4(oa[6].x, oa[6].y, oa[7].x, oa[7].y);
        float4* db = (float4*)(dst + (size_t)(t + 256) * NN2 + jb);
        db[0] = make_float4(ob[0].x, ob[0].y, ob[1].x, ob[1].y);
        db[1] = make_float4(ob[2].x, ob[2].y, ob[3].x, ob[3].y);
        db[2] = make_float4(ob[4].x, ob[4].y, ob[5].x, ob[5].y);
        db[3] = make_float4(ob[6].x, ob[6].y, ob[7].x, ob[7].y);
    }
}

// ---------------------------------------------------------------------------
// kB2T (plain, tail only): Zt[row][n1*1024 + j] -> time xT[n1*1024+n2]
// ---------------------------------------------------------------------------
__global__ __launch_bounds__(256) void kB2T(const cplx* __restrict__ in, cplx* __restrict__ out) {
    __shared__ cplx ld[1024 + 64];
    __shared__ cplx tw[TW_SZ];
    int row = blockIdx.y;
    int n1 = blockIdx.x;
    int tid = threadIdx.x;
    size_t base = (size_t)row * NTOT + (size_t)n1 * NN2;
    init_tw(tw, tid);
    __syncthreads();
    cplx y[4];
    fft_j2n2<-1>(in + base, y, ld, tw, tid);
    #pragma unroll
    for (int q = 0; q < 4; q++) out[base + tid + q * 256] = y[q];
}

// ---------------------------------------------------------------------------
// kNL: fused nonlinear kernel. 16 inverse conv FFTs (double-buffered ld) +
//   S-contraction + Kerr, then 4 forward FFTs of S_total -> Tbout.
// ---------------------------------------------------------------------------
__global__ __launch_bounds__(256) void kNL(const cplx* __restrict__ Zin, const cplx* __restrict__ A,
                                           const float* __restrict__ Sg, cplx* __restrict__ Tbout) {
    __shared__ cplx ld0[1024 + 64];
    __shared__ cplx ld1[1024 + 64];
    __shared__ cplx tw[TW_SZ];
    __shared__ float Ssh[256];
    int n1 = blockIdx.x, tid = threadIdx.x;
    Ssh[tid] = Sg[tid];
    init_tw(tw, tid);
    size_t base = (size_t)n1 * NN2;
    size_t tb = base + tid;
    cplx am[4][4];
    #pragma unroll
    for (int m = 0; m < 4; m++)
        #pragma unroll
        for (int q = 0; q < 4; q++) am[m][q] = A[(size_t)m * NTOT + tb + q * 256];
    cplx acc[4][4];
    #pragma unroll
    for (int p = 0; p < 4; p++)
        #pragma unroll
        for (int q = 0; q < 4; q++) acc[p][q] = make_float2(0.f, 0.f);
    __syncthreads();  // tw/Ssh ready
    for (int rowi = 0; rowi < 16; rowi++) {
        cplx* buf = (rowi & 1) ? ld1 : ld0;
        cplx tc[4];
        fft_j2n2<1>(Zin + (size_t)rowi * NTOT + base, tc, buf, tw, tid);
        int r = rowi >> 2, s = rowi & 3;
        #pragma unroll
        for (int q = 0; q < 4; q++) {
            #pragma unroll
            for (int p = 0; p < 4; p++) {
                float c0 = Ssh[((p * 4 + 0) * 4 + r) * 4 + s];
                float c1 = Ssh[((p * 4 + 1) * 4 + r) * 4 + s];
                float c2 = Ssh[((p * 4 + 2) * 4 + r) * 4 + s];
                float c3 = Ssh[((p * 4 + 3) * 4 + r) * 4 + s];
                cplx c;
                c.x = c0 * am[0][q].x + c1 * am[1][q].x + c2 * am[2][q].x + c3 * am[3][q].x;
                c.y = c0 * am[0][q].y + c1 * am[1][q].y + c2 * am[2][q].y + c3 * am[3][q].y;
                acc[p][q] = cadd(acc[p][q], cmul(c, tc[q]));
            }
        }
    }
    // Kerr + combine (acc becomes S_total)
    #pragma unroll
    for (int q = 0; q < 4; q++) {
        cplx pp[4][4];
        #pragma unroll
        for (int r = 0; r < 4; r++)
            #pragma unroll
            for (int s = 0; s < 4; s++) pp[r][s] = cmul(am[r][q], conjc(am[s][q]));
        #pragma unroll
        for (int p = 0; p < 4; p++) {
            cplx kc = make_float2(0.f, 0.f);
            #pragma unroll
            for (int m = 0; m < 4; m++) {
                cplx g = make_float2(0.f, 0.f);
                #pragma unroll
                for (int r = 0; r < 4; r++)
                    #pragma unroll
                    for (int s = 0; s < 4; s++) {
                        float coef = Ssh[((p * 4 + m) * 4 + r) * 4 + s];
                        g.x += coef * pp[r][s].x;
                        g.y += coef * pp[r][s].y;
                    }
                kc = cadd(kc, cmul(g, am[m][q]));
            }
            acc[p][q] = cadd(cscale(kc, 1.0f - FRv), cscale(acc[p][q], FRv));
        }
    }
    cplx w0 = expi_pi((float)(n1 * dig4rev10(4 * tid)) * (2.0f / (float)NTOT), 1.0f);
    cplx dlt = expi_pi((float)n1 * (1.0f / 1024.0f), 1.0f);
    #pragma unroll
    for (int p = 0; p < 4; p++) {
        cplx* buf = (p & 1) ? ld1 : ld0;
        cplx y[4] = {acc[p][0], acc[p][1], acc[p][2], acc[p][3]};
        fft_n22j<true>(y, buf, tw, tid, w0, dlt, Tbout + (size_t)p * NTOT + base);
    }
}

// ---------------------------------------------------------------------------
// kRK<STAGE>: knl spectrum Tbin -> time (fft over j) + RK4 update.
// ---------------------------------------------------------------------------
template <int STAGE>
__global__ __launch_bounds__(256) void kRK(const cplx* Tbin, const cplx* __restrict__ fP,
                                           cplx* __restrict__ kaccP, cplx* __restrict__ AtmpP,
                                           cplx* ZOut) {
    __shared__ cplx ld0[1024 + 64];
    __shared__ cplx ld1[1024 + 64];
    __shared__ cplx tw[TW_SZ];
    int n1 = blockIdx.x, tid = threadIdx.x;
    init_tw(tw, tid);
    __syncthreads();
    size_t base = (size_t)n1 * NN2;
    cplx an[4][4];
    #pragma unroll
    for (int p = 0; p < 4; p++) {
        cplx* buf = (p & 1) ? ld1 : ld0;
        cplx y[4];
        fft_j2n2<-1>(Tbin + (size_t)p * NTOT + base, y, buf, tw, tid);
        #pragma unroll
        for (int q = 0; q < 4; q++) {
            size_t off = (size_t)p * NTOT + base + tid + q * 256;
            cplx v = y[q];
            if (STAGE == 1) {
                kaccP[off] = v;
                an[p][q] = cadd(fP[off], cscale(v, 0.5f));
                AtmpP[off] = an[p][q];
            } else if (STAGE == 2) {
                kaccP[off] = cadd(kaccP[off], cscale(v, 2.0f));
                an[p][q] = cadd(fP[off], cscale(v, 0.5f));
                AtmpP[off] = an[p][q];
            } else if (STAGE == 3) {
                kaccP[off] = cadd(kaccP[off], cscale(v, 2.0f));
                an[p][q] = cadd(fP[off], v);
                AtmpP[off] = an[p][q];
            } else {
                an[p][q] = cadd(fP[off], cscale(cadd(kaccP[off], v), 1.0f / 6.0f));
            }
        }
    }
    const float SGN = (STAGE == 4) ? 1.0f : -1.0f;
    cplx w0 = expi_pi((float)(n1 * dig4rev10(4 * tid)) * (2.0f / (float)NTOT), SGN);
    cplx dlt = expi_pi((float)n1 * (1.0f / 1024.0f), SGN);
    if (STAGE <= 3) {
        #pragma unroll
        for (int rs = 0; rs < 16; rs++) {
            cplx* buf = (rs & 1) ? ld1 : ld0;
            int r = rs >> 2, s = rs & 3;
            cplx y[4];
            #pragma unroll
            for (int q = 0; q < 4; q++) y[q] = cmul(an[r][q], conjc(an[s][q]));
            fft_n22j<false>(y, buf, tw, tid, w0, dlt, ZOut + (size_t)rs * NTOT + base);
        }
    } else {
        #pragma unroll
        for (int p = 0; p < 4; p++) {
            cplx* buf = (p & 1) ? ld1 : ld0;
            cplx y[4] = {an[p][0], an[p][1], an[p][2], an[p][3]};
            fft_n22j<true>(y, buf, tw, tid, w0, dlt, ZOut + (size_t)p * NTOT + base);
        }
    }
}

// ---------------------------------------------------------------------------
// kBD: boundary tail. Tbin (post-kM lin^x spectrum) -> f (time, stored) and
//      TFORM products + 16 forward FFTs -> ZOut (stage-1 conv spectra).
// ---------------------------------------------------------------------------
__global__ __launch_bounds__(256) void kBD(const cplx* __restrict__ Tbin, cplx* __restrict__ fP,
                                           cplx* __restrict__ ZOut) {
    __shared__ cplx ld0[1024 + 64];
    __shared__ cplx ld1[1024 + 64];
    __shared__ cplx tw[TW_SZ];
    int n1 = blockIdx.x, tid = threadIdx.x;
    init_tw(tw, tid);
    __syncthreads();
    size_t base = (size_t)n1 * NN2;
    cplx an[4][4];
    #pragma unroll
    for (int p = 0; p < 4; p++) {
        cplx* buf = (p & 1) ? ld1 : ld0;
        cplx y[4];
        fft_j2n2<-1>(Tbin + (size_t)p * NTOT + base, y, buf, tw, tid);
        #pragma unroll
        for (int q = 0; q < 4; q++) {
            size_t off = (size_t)p * NTOT + base + tid + q * 256;
            an[p][q] = y[q];
            fP[off] = y[q];
        }
    }
    cplx w0 = expi_pi((float)(n1 * dig4rev10(4 * tid)) * (2.0f / (float)NTOT), -1.0f);
    cplx dlt = expi_pi((float)n1 * (1.0f / 1024.0f), -1.0f);
    #pragma unroll
    for (int rs = 0; rs < 16; rs++) {
        cplx* buf = (rs & 1) ? ld1 : ld0;
        int r = rs >> 2, s = rs & 3;
        cplx y[4];
        #pragma unroll
        for (int q = 0; q < 4; q++) y[q] = cmul(an[r][q], conjc(an[s][q]));
        fft_n22j<false>(y, buf, tw, tid, w0, dlt, ZOut + (size_t)rs * NTOT + base);
    }
}

// ---------------------------------------------------------------------------
// Pointwise kernels
// ---------------------------------------------------------------------------
__global__ __launch_bounds__(256) void k_tables(const float* __restrict__ D_re, const float* __restrict__ D_im,
                                                const float* __restrict__ hrw_re, const float* __restrict__ hrw_im,
                                                const float* __restrict__ omega,
                                                cplx* __restrict__ lin, cplx* __restrict__ pref, cplx* __restrict__ hrwc) {
    int k = blockIdx.x * 256 + threadIdx.x;
    if (k >= NTOT) return;
    int k2 = k & (NN2 - 1), k1 = k >> 10;
    int j = dig4rev10(k2), i = islot_512(k1);
    int s2 = j * NN1 + i;
    float om = omega[k];
    pref[s2] = make_float2(0.0f, GAMMAv * DZv * (1.0f + om / OMEGA0v));
    hrwc[s2] = make_float2(hrw_re[k] * DTv, -hrw_im[k] * DTv);
    for (int p = 0; p < PM; p++) {
        float dr = D_re[(size_t)p * NTOT + k], di = D_im[(size_t)p * NTOT + k];
        float amp = expf(-0.5f * DZv * di);
        float s, c;
        sincosf(0.5f * DZv * dr, &s, &c);
        lin[(size_t)p * NTOT + s2] = make_float2(amp * c, amp * s);
    }
}

__global__ void k_in(const float* __restrict__ Are, const float* __restrict__ Aim, cplx* __restrict__ f) {
    __shared__ cplx t[32][33];
    int p = blockIdx.z;
    int n1b = blockIdx.x * 32, n2b = blockIdx.y * 32;
    int tx = threadIdx.x, ty = threadIdx.y;
    const float* ar = Are + (size_t)p * NTOT;
    const float* ai = Aim + (size_t)p * NTOT;
    for (int yy = ty; yy < 32; yy += 8) {
        size_t idx = (size_t)(n2b + yy) * NN1 + (n1b + tx);
        t[yy][tx] = make_float2(ar[idx], ai[idx]);
    }
    __syncthreads();
    cplx* dst = f + (size_t)p * NTOT;
    for (int yy = ty; yy < 32; yy += 8) {
        dst[(size_t)(n1b + yy) * NN2 + (n2b + tx)] = t[tx][yy];
    }
}

__global__ void k_out(const cplx* __restrict__ fin, float* __restrict__ out) {
    __shared__ cplx t[32][33];
    int p = blockIdx.z;
    int n1b = blockIdx.x * 32, n2b = blockIdx.y * 32;
    int tx = threadIdx.x, ty = threadIdx.y;
    const cplx* src = fin + (size_t)p * NTOT;
    for (int yy = ty; yy < 32; yy += 8) {
        t[yy][tx] = src[(size_t)(n1b + yy) * NN2 + (n2b + tx)];
    }
    __syncthreads();
    float* outr = out + (size_t)p * NTOT;
    float* outi = out + (size_t)(PM + p) * NTOT;
    for (int yy = ty; yy < 32; yy += 8) {
        cplx v = t[tx][yy];
        size_t idx = (size_t)(n2b + yy) * NN1 + (n1b + tx);
        outr[idx] = v.x;
        outi[idx] = v.y;
    }
}

// ---------------------------------------------------------------------------
extern "C" void kernel_launch(void* const* d_in, const int* in_sizes, int n_in,
                              void* d_out, int out_size, void* d_ws, size_t ws_size,
                              hipStream_t stream) {
    const float* Are = (const float*)d_in[0];
    const float* Aim = (const float*)d_in[1];
    const float* S = (const float*)d_in[2];
    const float* Dre = (const float*)d_in[3];
    const float* Dim = (const float*)d_in[4];
    const float* hre = (const float*)d_in[5];
    const float* him = (const float*)d_in[6];
    const float* omega = (const float*)d_in[7];

    const size_t ROW = (size_t)NTOT;
    // ws rows: f(4) Atmp(4) kacc(4) lin(4) pref(1) hrwc(1) Tb(4) Z(16) = 38
    if (ws_size < 38ULL * ROW * sizeof(cplx)) return;
    cplx* f = (cplx*)d_ws;
    cplx* Atmp = f + 4 * ROW;
    cplx* kacc = Atmp + 4 * ROW;
    cplx* lin = kacc + 4 * ROW;
    cplx* pref = lin + 4 * ROW;
    cplx* hrwc = pref + 1 * ROW;
    cplx* Tb = hrwc + 1 * ROW;
    cplx* Z = Tb + 4 * ROW;

    dim3 b256(256);
    dim3 gT(16, 32, 4), bT(32, 8);
    dim3 gPW1(NTOT / 256);

    k_tables<<<gPW1, b256, 0, stream>>>(Dre, Dim, hre, him, omega, lin, pref, hrwc);
    k_in<<<gT, bT, 0, stream>>>(Are, Aim, f);
    // Tb = ifft-spectrum of A0  (boundary input)
    kA1<true><<<dim3(512, 4), b256, 0, stream>>>(f, Tb);

    for (int step = 0; step < NZ_STEPS; step++) {
        if (step == 0)
            kM<false, 1><<<dim3(128, 4), b256, 0, stream>>>(Tb, Tb, lin);
        else
            kM<false, 2><<<dim3(128, 4), b256, 0, stream>>>(Tb, Tb, lin);
        kBD<<<dim3(512), b256, 0, stream>>>(Tb, f, Z);
        for (int st = 1; st <= 4; st++) {
            const cplx* Aarg = (st == 1) ? f : Atmp;
            kM<true, 3><<<dim3(128, 16), b256, 0, stream>>>(Z, Z, hrwc);
            kNL<<<dim3(512), b256, 0, stream>>>(Z, Aarg, S, Tb);
            kM<false, 3><<<dim3(128, 4), b256, 0, stream>>>(Tb, Tb, pref);
            if (st == 1)
                kRK<1><<<dim3(512), b256, 0, stream>>>(Tb, f, kacc, Atmp, Z);
            else if (st == 2)
                kRK<2><<<dim3(512), b256, 0, stream>>>(Tb, f, kacc, Atmp, Z);
            else if (st == 3)
                kRK<3><<<dim3(512), b256, 0, stream>>>(Tb, f, kacc, Atmp, Z);
            else
                kRK<4><<<dim3(512), b256, 0, stream>>>(Tb, f, kacc, nullptr, Tb);
        }
    }
    // tail: out = fft(lin * ifft(f_final)) -> natural layout
    kM<false, 1><<<dim3(128, 4), b256, 0, stream>>>(Tb, Tb, lin);
    kB2T<<<dim3(512, 4), b256, 0, stream>>>(Tb, Atmp);
    k_out<<<gT, bT, 0, stream>>>(Atmp, (float*)d_out);
}